// Round 1
// baseline (1443.095 us; speedup 1.0000x reference)
//
#include <hip/hip_runtime.h>

// Problem: codes (1048576 x 256 f32), centroids (10 x 4 x 256 f32)
// -> out (1048576 x 10 f32): 1 - max_k dot(code, l2norm(centroid[c][k]))
//
// Memory-bound: 1.07 GB codes read @ ~6 TB/s => ~180 us floor.
// Strategy: bf16 MFMA (16x16x32) so compute (21.5 GFLOP) is trivially hidden;
// fp32 VALU path would need 137 us and risk poor overlap.

typedef short short8 __attribute__((ext_vector_type(8)));
typedef float floatx4 __attribute__((ext_vector_type(4)));

#define NUM_CLASSES 10
#define DIM 256
#define NPAD 48   // 40 centroids padded to 3 N-tiles of 16

// fp32 -> bf16 round-to-nearest-even (bit trick; no NaN inputs here)
__device__ inline short f2bf(float f) {
  union { float f; unsigned u; } v; v.f = f;
  unsigned u = v.u;
  u += 0x7fffu + ((u >> 16) & 1u);
  return (short)(u >> 16);
}

// One wave per centroid: L2-normalize (fp32) and store bf16, n-major [48][256].
// Waves 40..47 zero the padding rows.
__global__ void prep_centroids(const float* __restrict__ cents,
                               short* __restrict__ Bn) {
  int w = blockIdx.x * (blockDim.x >> 6) + (threadIdx.x >> 6);
  int lane = threadIdx.x & 63;
  if (w < 40) {
    const float4 x = *(const float4*)(cents + w * DIM + lane * 4);
    float ss = x.x * x.x + x.y * x.y + x.z * x.z + x.w * x.w;
    #pragma unroll
    for (int off = 32; off > 0; off >>= 1) ss += __shfl_xor(ss, off);
    float scale = 1.0f / fmaxf(sqrtf(ss), 1e-12f);
    short4 o;
    o.x = f2bf(x.x * scale);
    o.y = f2bf(x.y * scale);
    o.z = f2bf(x.z * scale);
    o.w = f2bf(x.w * scale);
    *(short4*)(Bn + w * DIM + lane * 4) = o;
  } else if (w < NPAD) {
    short4 z = {0, 0, 0, 0};
    *(short4*)(Bn + w * DIM + lane * 4) = z;
  }
}

// One wave per 16-row tile of codes. A fragments loaded straight from global
// in MFMA A-layout (lane: m = lane&15, k = quad*8 + j). Per wave per ktile the
// 64 lanes cover 16 rows x 128 contiguous bytes -> fully coalesced.
// B fragments (lane: n = lane&15, k = quad*8 + j) read from ws (L1/L2-hot).
__global__ __launch_bounds__(256) void dist_kernel(
    const float* __restrict__ codes, const short* __restrict__ Bn,
    float* __restrict__ out) {
  const int wave = blockIdx.x * 4 + (threadIdx.x >> 6);
  const int lane = threadIdx.x & 63;
  const int m = lane & 15;
  const int quad = lane >> 4;
  const long base = (long)wave * 16;

  const float* arow = codes + (base + m) * DIM + quad * 8;
  const short* b0 = Bn + (0 + m) * DIM + quad * 8;
  const short* b1 = Bn + (16 + m) * DIM + quad * 8;
  const short* b2 = Bn + (32 + m) * DIM + quad * 8;

  floatx4 acc0 = {0.f, 0.f, 0.f, 0.f};
  floatx4 acc1 = {0.f, 0.f, 0.f, 0.f};
  floatx4 acc2 = {0.f, 0.f, 0.f, 0.f};

  #pragma unroll
  for (int kt = 0; kt < 8; ++kt) {
    const float4 a0 = *(const float4*)(arow + kt * 32);
    const float4 a1 = *(const float4*)(arow + kt * 32 + 4);
    short8 af;
    af[0] = f2bf(a0.x); af[1] = f2bf(a0.y);
    af[2] = f2bf(a0.z); af[3] = f2bf(a0.w);
    af[4] = f2bf(a1.x); af[5] = f2bf(a1.y);
    af[6] = f2bf(a1.z); af[7] = f2bf(a1.w);
    const short8 bf0 = *(const short8*)(b0 + kt * 32);
    const short8 bf1 = *(const short8*)(b1 + kt * 32);
    const short8 bf2 = *(const short8*)(b2 + kt * 32);
    acc0 = __builtin_amdgcn_mfma_f32_16x16x32_bf16(af, bf0, acc0, 0, 0, 0);
    acc1 = __builtin_amdgcn_mfma_f32_16x16x32_bf16(af, bf1, acc1, 0, 0, 0);
    acc2 = __builtin_amdgcn_mfma_f32_16x16x32_bf16(af, bf2, acc2, 0, 0, 0);
  }

  // C/D layout: col = lane&15 (centroid), row = quad*4 + reg.
  // class = centroid >> 2; max over the 4 centroids = max over aligned
  // 4-lane group -> shfl_xor(1), shfl_xor(2).
  const int cls_in = m >> 2;
  #pragma unroll
  for (int j = 0; j < 3; ++j) {
    const floatx4 a = (j == 0) ? acc0 : (j == 1) ? acc1 : acc2;
    const int cls = j * 4 + cls_in;
    #pragma unroll
    for (int r = 0; r < 4; ++r) {
      float v = a[r];
      v = fmaxf(v, __shfl_xor(v, 1));
      v = fmaxf(v, __shfl_xor(v, 2));
      if ((lane & 3) == 0 && cls < NUM_CLASSES) {
        const long row = base + quad * 4 + r;
        out[row * NUM_CLASSES + cls] = 1.0f - v;
      }
    }
  }
}

extern "C" void kernel_launch(void* const* d_in, const int* in_sizes, int n_in,
                              void* d_out, int out_size, void* d_ws,
                              size_t ws_size, hipStream_t stream) {
  const float* codes = (const float*)d_in[0];      // (1048576, 256) f32
  const float* cents = (const float*)d_in[1];      // (10, 4, 256) f32
  float* out = (float*)d_out;                      // (1048576, 10) f32
  short* Bn = (short*)d_ws;                        // [48][256] bf16 (as short)

  const int batch = in_sizes[0] / DIM;             // 1048576
  const int tiles = batch / 16;                    // 65536 waves
  const int blocks = tiles / 4;                    // 4 waves per block

  prep_centroids<<<dim3(12), dim3(256), 0, stream>>>(cents, Bn);
  dist_kernel<<<dim3(blocks), dim3(256), 0, stream>>>(codes, Bn, out);
}